// Round 3
// baseline (470.668 us; speedup 1.0000x reference)
//
#include <hip/hip_runtime.h>

// (B,C,H,W) = (4,16,320,640), fp32 throughout.
constexpr int Bn = 4;
constexpr int Cn = 16;
constexpr int Hn = 320;
constexpr int Wn = 640;
constexpr int NCOL = Bn * Cn * Wn;   // 40960 vertical columns
constexpr int NROW = Bn * Cn * Hn;   // 20480 horizontal rows

// ---------------------------------------------------------------------------
// Vertical, two-pass carry scheme, both directions in one block.
// Block = 640 threads = 10 waves; wave s owns a 32-row segment of the same 64
// columns for BOTH the down scan (g0) and the up scan (g1).
// Phase A: per-segment summary (A,B) only -> 2 live regs, loads stream deep.
// Phase B: 64+64 threads stitch carries serially in LDS.
// Phase C: recompute recurrence with true carry as init, store results.
// Recurrence: y = b*y_prev + x*(1-b) == fma(b, y_prev - x, x); b=0 at head.
// ---------------------------------------------------------------------------
constexpr int HSEG = 32;
constexpr int NSEG = Hn / HSEG;      // 10
constexpr int VBLK = NSEG * 64;      // 640 threads

__global__ __launch_bounds__(VBLK, 6) void vert2(
    const float* __restrict__ x, const float* __restrict__ g0,
    const float* __restrict__ g1, float* __restrict__ outD,
    float* __restrict__ outU) {
  __shared__ float A0[NSEG][64], B0[NSEG][64], A1[NSEG][64], B1[NSEG][64];
  int grp = blockIdx.x;
  int bc = grp / (Wn / 64);
  int w0 = (grp % (Wn / 64)) * 64;
  int s = threadIdx.x >> 6;
  int l = threadIdx.x & 63;
  size_t colbase = (size_t)bc * (Hn * Wn) + w0 + l;

  // ---- phase A: segment summaries ----
  {
    size_t off = colbase + (size_t)(s * HSEG) * Wn;
    float a = 0.0f, b = 1.0f;
#pragma unroll
    for (int i = 0; i < HSEG; ++i) {
      float xv = x[off];
      float gv = g0[off];
      float bb = (s == 0 && i == 0) ? 0.0f : gv;
      a = fmaf(bb, a - xv, xv);
      b *= bb;
      off += Wn;
    }
    A0[s][l] = a; B0[s][l] = b;
  }
  {
    size_t off = colbase + (size_t)(Hn - 1 - s * HSEG) * Wn;
    float a = 0.0f, b = 1.0f;
#pragma unroll
    for (int i = 0; i < HSEG; ++i) {
      float xv = x[off];
      float gv = g1[off];
      float bb = (s == 0 && i == 0) ? 0.0f : gv;
      a = fmaf(bb, a - xv, xv);
      b *= bb;
      off -= Wn;
    }
    A1[s][l] = a; B1[s][l] = b;
  }
  __syncthreads();

  // ---- phase B: carry stitch (wave 0 = down, wave 1 = up; wave-uniform) ----
  if (threadIdx.x < 128) {
    bool d1 = threadIdx.x >= 64;
    int ll = threadIdx.x & 63;
    float c = 0.0f;
#pragma unroll
    for (int ss = 0; ss < NSEG; ++ss) {
      float a = d1 ? A1[ss][ll] : A0[ss][ll];
      float b = d1 ? B1[ss][ll] : B0[ss][ll];
      if (d1) A1[ss][ll] = c; else A0[ss][ll] = c;   // carry-in for segment ss
      c = fmaf(b, c, a);
    }
  }
  __syncthreads();

  // ---- phase C: recompute with true carry, store ----
  {
    float y = A0[s][l];
    size_t off = colbase + (size_t)(s * HSEG) * Wn;
#pragma unroll
    for (int i = 0; i < HSEG; ++i) {
      float xv = x[off];
      float gv = g0[off];
      float bb = (s == 0 && i == 0) ? 0.0f : gv;
      y = fmaf(bb, y - xv, xv);
      outD[off] = y;
      off += Wn;
    }
  }
  {
    float y = A1[s][l];
    size_t off = colbase + (size_t)(Hn - 1 - s * HSEG) * Wn;
#pragma unroll
    for (int i = 0; i < HSEG; ++i) {
      float xv = x[off];
      float gv = g1[off];
      float bb = (s == 0 && i == 0) ? 0.0f : gv;
      y = fmaf(bb, y - xv, xv);
      outU[off] = y;
      off -= Wn;
    }
  }
}

// Fallback if workspace unusable: per-thread fwd scan then bwd RMW-max.
__global__ __launch_bounds__(256) void vert_fused(
    const float* __restrict__ x, const float* __restrict__ g0,
    const float* __restrict__ g1, float* __restrict__ out) {
  int col = blockIdx.x * 256 + threadIdx.x;
  int w = col % Wn;
  int bc = col / Wn;
  size_t base = (size_t)bc * Hn * Wn + w;
  const float* xp = x + base;
  float* op = out + base;
  {
    const float* gp = g0 + base;
    float y = xp[0];
    op[0] = y;
#pragma unroll 8
    for (int h = 1; h < Hn; ++h) {
      float xv = xp[(size_t)h * Wn];
      float gv = gp[(size_t)h * Wn];
      y = fmaf(gv, y - xv, xv);
      op[(size_t)h * Wn] = y;
    }
  }
  {
    const float* gp = g1 + base;
    float y = xp[(size_t)(Hn - 1) * Wn];
    op[(size_t)(Hn - 1) * Wn] = fmaxf(op[(size_t)(Hn - 1) * Wn], y);
#pragma unroll 8
    for (int h = Hn - 2; h >= 0; --h) {
      float xv = xp[(size_t)h * Wn];
      float gv = gp[(size_t)h * Wn];
      y = fmaf(gv, y - xv, xv);
      op[(size_t)h * Wn] = fmaxf(op[(size_t)h * Wn], y);
    }
  }
}

// ---------------------------------------------------------------------------
// Horizontal: block = 256 threads = 4 waves, 4 consecutive rows per block.
// Stage x/g2/g3 into LDS with fully-coalesced float4 loads. One wave per row
// does the lane-segmented scan (WSEG=10, all 64 lanes active) from LDS, with
// one 6-step shuffle scan of (A,B) per direction. rr/rl overwrite the g
// staging buffers in-place; final 4-way max + store is coalesced float4.
// ---------------------------------------------------------------------------
constexpr int WSEG = 10;             // 64 lanes * 10 = 640

template <bool HAS_UP>
__global__ __launch_bounds__(256) void horiz3(
    const float* __restrict__ x, const float* __restrict__ g2,
    const float* __restrict__ g3, const float* __restrict__ down,
    const float* __restrict__ up, float* __restrict__ out) {
  __shared__ float xs[4 * Wn], rrs[4 * Wn], rls[4 * Wn];   // 30 KB
  const int tid = threadIdx.x, wv = tid >> 6, l = tid & 63;
  const size_t rowbase = (size_t)blockIdx.x * 4 * Wn;      // 4 rows contiguous

  // ---- stage (coalesced float4) ----
  const float4* xg = (const float4*)(x + rowbase);
  const float4* g2g = (const float4*)(g2 + rowbase);
  const float4* g3g = (const float4*)(g3 + rowbase);
  float4* xsv = (float4*)xs;
  float4* rrv = (float4*)rrs;
  float4* rlv = (float4*)rls;
#pragma unroll
  for (int i = tid; i < Wn; i += 256) {   // 640 float4s across 4 rows
    xsv[i] = xg[i];
    rrv[i] = g2g[i];
    rlv[i] = g3g[i];
  }
  __syncthreads();

  const int rb = wv * Wn + l * WSEG;
  float xl[WSEG], gl[WSEG], yl[WSEG], pl[WSEG];
#pragma unroll
  for (int i = 0; i < WSEG; ++i) { xl[i] = xs[rb + i]; gl[i] = rrs[rb + i]; }

  // ---- forward (r_right) ----
  {
    float y = 0.0f, p = 1.0f;
#pragma unroll
    for (int i = 0; i < WSEG; ++i) {
      float bb = (l == 0 && i == 0) ? 0.0f : gl[i];
      y = fmaf(bb, y - xl[i], xl[i]);
      p *= bb;
      yl[i] = y; pl[i] = p;
    }
    float A = y, B = p;
#pragma unroll
    for (int off = 1; off < 64; off <<= 1) {
      float Au = __shfl_up(A, off);
      float Bu = __shfl_up(B, off);
      if (l >= off) { A = fmaf(B, Au, A); B *= Bu; }
    }
    float c = __shfl_up(A, 1);
    if (l == 0) c = 0.0f;
#pragma unroll
    for (int i = 0; i < WSEG; ++i) rrs[rb + i] = fmaf(pl[i], c, yl[i]);
  }

  // ---- backward (r_left) ----
#pragma unroll
  for (int i = 0; i < WSEG; ++i) gl[i] = rls[rb + i];
  {
    float y = 0.0f, p = 1.0f;
#pragma unroll
    for (int i = WSEG - 1; i >= 0; --i) {
      float bb = (l == 63 && i == WSEG - 1) ? 0.0f : gl[i];
      y = fmaf(bb, y - xl[i], xl[i]);
      p *= bb;
      yl[i] = y; pl[i] = p;
    }
    float A = y, B = p;
#pragma unroll
    for (int off = 1; off < 64; off <<= 1) {
      float Ad = __shfl_down(A, off);
      float Bd = __shfl_down(B, off);
      if (l + off < 64) { A = fmaf(B, Ad, A); B *= Bd; }
    }
    float c = __shfl_down(A, 1);
    if (l == 63) c = 0.0f;
#pragma unroll
    for (int i = 0; i < WSEG; ++i) rls[rb + i] = fmaf(pl[i], c, yl[i]);
  }
  __syncthreads();

  // ---- fused 4-way max + store (coalesced float4) ----
  const float4* dn4 = (const float4*)(down + rowbase);
  const float4* up4 = (const float4*)(up + rowbase);
  float4* o4 = (float4*)(out + rowbase);
#pragma unroll
  for (int i = tid; i < Wn; i += 256) {
    float4 a = rrv[i];
    float4 b = rlv[i];
    float4 d = dn4[i];
    float4 o;
    o.x = fmaxf(fmaxf(a.x, b.x), d.x);
    o.y = fmaxf(fmaxf(a.y, b.y), d.y);
    o.z = fmaxf(fmaxf(a.z, b.z), d.z);
    o.w = fmaxf(fmaxf(a.w, b.w), d.w);
    if (HAS_UP) {
      float4 u = up4[i];
      o.x = fmaxf(o.x, u.x);
      o.y = fmaxf(o.y, u.y);
      o.z = fmaxf(o.z, u.z);
      o.w = fmaxf(o.w, u.w);
    }
    o4[i] = o;
  }
}

extern "C" void kernel_launch(void* const* d_in, const int* in_sizes, int n_in,
                              void* d_out, int out_size, void* d_ws,
                              size_t ws_size, hipStream_t stream) {
  const float* x = (const float*)d_in[0];
  const float* g0 = (const float*)d_in[1];
  const float* g1 = (const float*)d_in[2];
  const float* g2 = (const float*)d_in[3];
  const float* g3 = (const float*)d_in[4];
  float* out = (float*)d_out;

  size_t need = (size_t)out_size * sizeof(float);
  if (ws_size >= need) {
    float* ws = (float*)d_ws;
    // vert2 writes r_down -> out, r_up -> ws (both directions, one kernel)
    vert2<<<NCOL / 64, VBLK, 0, stream>>>(x, g0, g1, out, ws);
    horiz3<true><<<NROW / 4, 256, 0, stream>>>(x, g2, g3, out, ws, out);
  } else {
    vert_fused<<<NCOL / 256, 256, 0, stream>>>(x, g0, g1, out);
    horiz3<false><<<NROW / 4, 256, 0, stream>>>(x, g2, g3, out, nullptr, out);
  }
}

// Round 4
// 278.039 us; speedup vs baseline: 1.6928x; 1.6928x over previous
//
#include <hip/hip_runtime.h>

// (B,C,H,W) = (4,16,320,640), fp32 throughout.
constexpr int Bn = 4;
constexpr int Cn = 16;
constexpr int Hn = 320;
constexpr int Wn = 640;
constexpr int NCOL = Bn * Cn * Wn;   // 40960 vertical columns
constexpr int NROW = Bn * Cn * Hn;   // 20480 horizontal rows

// ---------------------------------------------------------------------------
// Vertical, both directions in one block, one-pass register scan per phase.
// Block = 1024 threads = 16 waves; wave s owns a 20-row segment of the same
// 64 consecutive columns. Phase DOWN: local scan in regs (y[20], P[20]),
// LDS carry stitch, fixup + store raw r_down into vm(=out). Phase UP: same
// with g1 on reversed rows; fixup does vm = max(vm, r_up). The readback of
// vm is the block's own 80 KB footprint -> L2/MALL-hot.
// Recurrence: y = g*y_prev + x*(1-g) == fma(g, y_prev - x, x); g:=0 at head.
// ---------------------------------------------------------------------------
constexpr int HS = 20;               // rows per segment
constexpr int NS = 16;               // segments = waves per block
constexpr int GPW = Wn / 64;         // 10 column-groups per image width

__global__ __launch_bounds__(1024, 8) void vert_both(
    const float* __restrict__ x, const float* __restrict__ g0,
    const float* __restrict__ g1, float* __restrict__ vm) {
  __shared__ float As[NS][64], Bs[NS][64];
  const int grp = blockIdx.x;              // 640 groups
  const int bc = grp / GPW;
  const int w0 = (grp % GPW) * 64;
  const int s = threadIdx.x >> 6;
  const int l = threadIdx.x & 63;
  const int colbase = bc * (Hn * Wn) + w0 + l;   // < 2^24, int is fine

  float y[HS], P[HS];

  // ================= DOWN (g0, rows ascending) =================
  {
    int off = colbase + (s * HS) * Wn;
    float yy = 0.0f, pp = 1.0f;
#pragma unroll
    for (int i = 0; i < HS; ++i) {
      float xv = x[off];
      float gv = g0[off];
      float bb = (s == 0 && i == 0) ? 0.0f : gv;
      yy = fmaf(bb, yy - xv, xv);
      pp *= bb;
      y[i] = yy;
      P[i] = pp;
      off += Wn;
    }
    As[s][l] = yy;
    Bs[s][l] = pp;
  }
  __syncthreads();
  if (threadIdx.x < 64) {                  // wave 0: serial carry stitch
    float c = 0.0f;
#pragma unroll
    for (int ss = 0; ss < NS; ++ss) {
      float a = As[ss][l], b = Bs[ss][l];
      As[ss][l] = c;                       // carry-in for segment ss
      c = fmaf(b, c, a);
    }
  }
  __syncthreads();
  {
    float c = As[s][l];
    int off = colbase + (s * HS) * Wn;
#pragma unroll
    for (int i = 0; i < HS; ++i) {
      vm[off] = fmaf(P[i], c, y[i]);
      off += Wn;
    }
  }
  __syncthreads();                         // stitch-read done; safe to reuse LDS

  // ================= UP (g1, rows descending) =================
  {
    int off = colbase + (Hn - 1 - s * HS) * Wn;
    float yy = 0.0f, pp = 1.0f;
#pragma unroll
    for (int i = 0; i < HS; ++i) {
      float xv = x[off];
      float gv = g1[off];
      float bb = (s == 0 && i == 0) ? 0.0f : gv;
      yy = fmaf(bb, yy - xv, xv);
      pp *= bb;
      y[i] = yy;
      P[i] = pp;
      off -= Wn;
    }
    As[s][l] = yy;
    Bs[s][l] = pp;
  }
  __syncthreads();
  if (threadIdx.x < 64) {
    float c = 0.0f;
#pragma unroll
    for (int ss = 0; ss < NS; ++ss) {
      float a = As[ss][l], b = Bs[ss][l];
      As[ss][l] = c;
      c = fmaf(b, c, a);
    }
  }
  __syncthreads();
  {
    float c = As[s][l];
    int off = colbase + (Hn - 1 - s * HS) * Wn;
#pragma unroll
    for (int i = 0; i < HS; ++i) {
      float u = fmaf(P[i], c, y[i]);       // r_up
      vm[off] = fmaxf(vm[off], u);         // max(r_down, r_up); readback L2-hot
      off -= Wn;
    }
  }
}

// ---------------------------------------------------------------------------
// Horizontal + final: block = 256 threads = 4 waves, 4 consecutive rows.
// Stage x/g2/g3 into LDS with coalesced float4 loads; prefetch vm(=out) into
// registers at the same time. One wave per row does the lane-segmented scan
// (WSEG=10) from LDS with one 6-step shuffle scan of (A,B) per direction.
// Final: out = max(r_right, r_left, vm) — same lines this block read.
// ---------------------------------------------------------------------------
constexpr int WSEG = 10;                   // 64 lanes * 10 = 640

__global__ __launch_bounds__(256) void horiz_final(
    const float* __restrict__ x, const float* __restrict__ g2,
    const float* __restrict__ g3, const float* __restrict__ vm,
    float* __restrict__ out) {
  __shared__ float xs[4 * Wn], rrs[4 * Wn], rls[4 * Wn];   // 30 KB
  const int tid = threadIdx.x, wv = tid >> 6, l = tid & 63;
  const size_t rowbase = (size_t)blockIdx.x * 4 * Wn;      // 4 rows contiguous

  const float4* xg = (const float4*)(x + rowbase);
  const float4* g2g = (const float4*)(g2 + rowbase);
  const float4* g3g = (const float4*)(g3 + rowbase);
  const float4* vm4 = (const float4*)(vm + rowbase);
  float4* xsv = (float4*)xs;
  float4* rrv = (float4*)rrs;
  float4* rlv = (float4*)rls;

  // ---- stage (coalesced float4); vm prefetched into registers ----
  const int i0 = tid, i1 = tid + 256, i2 = tid + 512;      // i2 valid if tid<128
  float4 v0, v1, v2;
  xsv[i0] = xg[i0]; rrv[i0] = g2g[i0]; rlv[i0] = g3g[i0]; v0 = vm4[i0];
  xsv[i1] = xg[i1]; rrv[i1] = g2g[i1]; rlv[i1] = g3g[i1]; v1 = vm4[i1];
  if (i2 < Wn) { xsv[i2] = xg[i2]; rrv[i2] = g2g[i2]; rlv[i2] = g3g[i2]; v2 = vm4[i2]; }
  __syncthreads();

  const int rb = wv * Wn + l * WSEG;
  float xl[WSEG], gl[WSEG], yl[WSEG], pl[WSEG];
#pragma unroll
  for (int i = 0; i < WSEG; ++i) { xl[i] = xs[rb + i]; gl[i] = rrs[rb + i]; }

  // ---- forward (r_right) ----
  {
    float y = 0.0f, p = 1.0f;
#pragma unroll
    for (int i = 0; i < WSEG; ++i) {
      float bb = (l == 0 && i == 0) ? 0.0f : gl[i];
      y = fmaf(bb, y - xl[i], xl[i]);
      p *= bb;
      yl[i] = y; pl[i] = p;
    }
    float A = y, B = p;
#pragma unroll
    for (int off = 1; off < 64; off <<= 1) {
      float Au = __shfl_up(A, off);
      float Bu = __shfl_up(B, off);
      if (l >= off) { A = fmaf(B, Au, A); B *= Bu; }
    }
    float c = __shfl_up(A, 1);
    if (l == 0) c = 0.0f;
#pragma unroll
    for (int i = 0; i < WSEG; ++i) rrs[rb + i] = fmaf(pl[i], c, yl[i]);
  }

  // ---- backward (r_left) ----
#pragma unroll
  for (int i = 0; i < WSEG; ++i) gl[i] = rls[rb + i];
  {
    float y = 0.0f, p = 1.0f;
#pragma unroll
    for (int i = WSEG - 1; i >= 0; --i) {
      float bb = (l == 63 && i == WSEG - 1) ? 0.0f : gl[i];
      y = fmaf(bb, y - xl[i], xl[i]);
      p *= bb;
      yl[i] = y; pl[i] = p;
    }
    float A = y, B = p;
#pragma unroll
    for (int off = 1; off < 64; off <<= 1) {
      float Ad = __shfl_down(A, off);
      float Bd = __shfl_down(B, off);
      if (l + off < 64) { A = fmaf(B, Ad, A); B *= Bd; }
    }
    float c = __shfl_down(A, 1);
    if (l == 63) c = 0.0f;
#pragma unroll
    for (int i = 0; i < WSEG; ++i) rls[rb + i] = fmaf(pl[i], c, yl[i]);
  }
  __syncthreads();

  // ---- fused final max + store (coalesced float4) ----
  float4* o4 = (float4*)(out + rowbase);
  {
    float4 a = rrv[i0], b = rlv[i0];
    float4 o;
    o.x = fmaxf(fmaxf(a.x, b.x), v0.x);
    o.y = fmaxf(fmaxf(a.y, b.y), v0.y);
    o.z = fmaxf(fmaxf(a.z, b.z), v0.z);
    o.w = fmaxf(fmaxf(a.w, b.w), v0.w);
    o4[i0] = o;
  }
  {
    float4 a = rrv[i1], b = rlv[i1];
    float4 o;
    o.x = fmaxf(fmaxf(a.x, b.x), v1.x);
    o.y = fmaxf(fmaxf(a.y, b.y), v1.y);
    o.z = fmaxf(fmaxf(a.z, b.z), v1.z);
    o.w = fmaxf(fmaxf(a.w, b.w), v1.w);
    o4[i1] = o;
  }
  if (i2 < Wn) {
    float4 a = rrv[i2], b = rlv[i2];
    float4 o;
    o.x = fmaxf(fmaxf(a.x, b.x), v2.x);
    o.y = fmaxf(fmaxf(a.y, b.y), v2.y);
    o.z = fmaxf(fmaxf(a.z, b.z), v2.z);
    o.w = fmaxf(fmaxf(a.w, b.w), v2.w);
    o4[i2] = o;
  }
}

extern "C" void kernel_launch(void* const* d_in, const int* in_sizes, int n_in,
                              void* d_out, int out_size, void* d_ws,
                              size_t ws_size, hipStream_t stream) {
  const float* x = (const float*)d_in[0];
  const float* g0 = (const float*)d_in[1];
  const float* g1 = (const float*)d_in[2];
  const float* g2 = (const float*)d_in[3];
  const float* g3 = (const float*)d_in[4];
  float* out = (float*)d_out;

  // vert_both writes max(r_down, r_up) into out; horiz_final consumes it
  // (block-local lines) and overwrites with the final 4-way max. No ws use.
  vert_both<<<NCOL / 64, 1024, 0, stream>>>(x, g0, g1, out);
  horiz_final<<<NROW / 4, 256, 0, stream>>>(x, g2, g3, out, out);
}